// Round 1
// baseline (918.699 us; speedup 1.0000x reference)
//
#include <hip/hip_runtime.h>
#include <hip/hip_bf16.h>
#include <math.h>

#define D 8192
#define D4 (D / 4)
#define GAMMA 0.95f

// ---------- wave (64-lane) reductions ----------
__device__ inline float wred_sum(float v) {
    for (int o = 32; o > 0; o >>= 1) v += __shfl_down(v, o, 64);
    return v;
}
__device__ inline float wred_min(float v) {
    for (int o = 32; o > 0; o >>= 1) v = fminf(v, __shfl_down(v, o, 64));
    return v;
}
__device__ inline float wred_max(float v) {
    for (int o = 32; o > 0; o >>= 1) v = fmaxf(v, __shfl_down(v, o, 64));
    return v;
}
__device__ inline int wred_imin(int v) {
    for (int o = 32; o > 0; o >>= 1) v = min(v, __shfl_down(v, o, 64));
    return v;
}

// ---------- pass A: per-column dot(k, MK[:,j]) and sum(MK[:,j]^2) ----------
// grid (8, 128), block 256. Each thread owns 4 consecutive columns (float4).
__global__ __launch_bounds__(256) void pass_a(const float* __restrict__ MK,
                                              const float* __restrict__ k,
                                              float* __restrict__ dot,
                                              float* __restrict__ sq) {
    const int ROWS = 64;
    const int j4 = blockIdx.x * 256 + threadIdx.x;   // 0..2047
    const int i0 = blockIdx.y * ROWS;
    const float4* MK4 = (const float4*)MK;
    float4 d = make_float4(0.f, 0.f, 0.f, 0.f);
    float4 s = make_float4(0.f, 0.f, 0.f, 0.f);
    for (int r = 0; r < ROWS; ++r) {
        const int i = i0 + r;
        const float kv = k[i];                        // wave-uniform -> scalar load
        const float4 m = MK4[(size_t)i * D4 + j4];
        d.x += kv * m.x; d.y += kv * m.y; d.z += kv * m.z; d.w += kv * m.w;
        s.x += m.x * m.x; s.y += m.y * m.y; s.z += m.z * m.z; s.w += m.w * m.w;
    }
    const int j = j4 * 4;
    atomicAdd(&dot[j + 0], d.x); atomicAdd(&dot[j + 1], d.y);
    atomicAdd(&dot[j + 2], d.z); atomicAdd(&dot[j + 3], d.w);
    atomicAdd(&sq[j + 0], s.x);  atomicAdd(&sq[j + 1], s.y);
    atomicAdd(&sq[j + 2], s.z);  atomicAdd(&sq[j + 3], s.w);
}

// ---------- small kernel: softmax addressing + all vector updates ----------
// single block, 1024 threads, each owns 8 slots (j = t + p*1024).
__global__ __launch_bounds__(1024) void kern_small(
    const float* __restrict__ k, const float* __restrict__ u,
    const float* __restrict__ w_w, const float* __restrict__ w_u,
    const float* __restrict__ w_lu, const float* __restrict__ beta_p,
    float* __restrict__ dot_wr,   // in: dot, out: w_r
    float* __restrict__ sq_ak,    // in: sq,  out: add_k = w_u_new * k
    float* __restrict__ add_u,    // out: w_w_new * u
    int* __restrict__ mip,        // out: argmin index
    float* __restrict__ o_www, float* __restrict__ o_wun, float* __restrict__ o_wlu) {
    __shared__ float sh[16];
    __shared__ int shi[16];
    __shared__ float f_k2, f_minwu, f_maxsim, f_sumexp, f_minwun;
    const int t = threadIdx.x, lane = t & 63, wid = t >> 6;

    // ---- local loads + ||k||^2 + min(w_u) ----
    float kv[8], wuv[8];
    float a = 0.f, mn = INFINITY;
#pragma unroll
    for (int p = 0; p < 8; ++p) {
        const int j = t + p * 1024;
        kv[p] = k[j];
        wuv[p] = w_u[j];
        a += kv[p] * kv[p];
        mn = fminf(mn, wuv[p]);
    }
    float rs = wred_sum(a);
    if (lane == 0) sh[wid] = rs;
    __syncthreads();
    if (t == 0) { float s = 0.f; for (int w = 0; w < 16; ++w) s += sh[w]; f_k2 = s; }
    __syncthreads();

    float rmn = wred_min(mn);
    if (lane == 0) sh[wid] = rmn;
    __syncthreads();
    if (t == 0) { float m = sh[0]; for (int w = 1; w < 16; ++w) m = fminf(m, sh[w]); f_minwu = m; }
    __syncthreads();

    // ---- first index attaining min(w_u) (jnp.argmin semantics) ----
    const float minwu = f_minwu;
    int mi = 0x7fffffff;
#pragma unroll
    for (int p = 0; p < 8; ++p) {
        const int j = t + p * 1024;
        if (wuv[p] == minwu) mi = min(mi, j);
    }
    int rmi = wred_imin(mi);
    if (lane == 0) shi[wid] = rmi;
    __syncthreads();
    if (t == 0) { int m = shi[0]; for (int w = 1; w < 16; ++w) m = min(m, shi[w]); mip[0] = m; }

    // ---- cosine similarity + softmax ----
    const float inv_nk = 1.f / sqrtf(f_k2);
    float sim[8];
    float mx = -INFINITY;
#pragma unroll
    for (int p = 0; p < 8; ++p) {
        const int j = t + p * 1024;
        sim[p] = dot_wr[j] * inv_nk / sqrtf(sq_ak[j]);
        mx = fmaxf(mx, sim[p]);
    }
    float rmx = wred_max(mx);
    __syncthreads();               // protect sh reuse (argmin phase readers done)
    if (lane == 0) sh[wid] = rmx;
    __syncthreads();
    if (t == 0) { float m = sh[0]; for (int w = 1; w < 16; ++w) m = fmaxf(m, sh[w]); f_maxsim = m; }
    __syncthreads();

    const float M = f_maxsim;
    float e[8];
    float se = 0.f;
#pragma unroll
    for (int p = 0; p < 8; ++p) { e[p] = expf(sim[p] - M); se += e[p]; }
    float rse = wred_sum(se);
    if (lane == 0) sh[wid] = rse;
    __syncthreads();
    if (t == 0) { float s = 0.f; for (int w = 0; w < 16; ++w) s += sh[w]; f_sumexp = s; }
    __syncthreads();

    const float inv_se = 1.f / f_sumexp;
    const float beta = 1.f / (1.f + expf(-beta_p[0]));

    // ---- w updates + precomputed broadcast vectors ----
    float wun[8];
    float mnw = INFINITY;
#pragma unroll
    for (int p = 0; p < 8; ++p) {
        const int j = t + p * 1024;
        const float wr = e[p] * inv_se;
        const float wwn = beta * wr + (1.f - beta) * w_lu[j];
        wun[p] = GAMMA * wuv[p] + wr + w_w[j];
        dot_wr[j] = wr;                 // overwrite dot with w_r
        sq_ak[j] = wun[p] * kv[p];      // overwrite sq with add_k
        add_u[j] = wwn * u[j];
        o_www[j] = wwn;
        o_wun[j] = wun[p];
        mnw = fminf(mnw, wun[p]);
    }
    float rmw = wred_min(mnw);
    __syncthreads();
    if (lane == 0) sh[wid] = rmw;
    __syncthreads();
    if (t == 0) { float m = sh[0]; for (int w = 1; w < 16; ++w) m = fminf(m, sh[w]); f_minwun = m; }
    __syncthreads();

    const float mw = f_minwun;
#pragma unroll
    for (int p = 0; p < 8; ++p) {
        const int j = t + p * 1024;
        o_wlu[j] = (wun[p] < mw) ? 1.f : 0.f;   // strict less: faithful (all zeros)
    }
}

// ---------- pass B: u_final = mk @ w_r^T  and  mk_new = mk + add_k ----------
// 1024 blocks x 256 threads; block handles 8 full rows (no atomics).
__global__ __launch_bounds__(256) void pass_b(const float* __restrict__ MK,
                                              const float* __restrict__ w_r,
                                              const float* __restrict__ add_k,
                                              const int* __restrict__ mip,
                                              float* __restrict__ out_u,
                                              float* __restrict__ out_mk) {
    const int R = 8;
    const int row0 = blockIdx.x * R;
    const int t = threadIdx.x;
    const int mi = mip[0];
    const int mi4 = mi >> 2, mic = mi & 3;
    const float4* MK4 = (const float4*)MK;
    float4* OMK4 = (float4*)out_mk;
    const float4* WR4 = (const float4*)w_r;
    const float4* AK4 = (const float4*)add_k;

    float4 wr[8], ak[8];
#pragma unroll
    for (int p = 0; p < 8; ++p) {
        const int j4 = p * 256 + t;
        wr[p] = WR4[j4];
        ak[p] = AK4[j4];
    }

    float racc[R];
#pragma unroll
    for (int r = 0; r < R; ++r) racc[r] = 0.f;

    for (int r = 0; r < R; ++r) {
        const size_t base = (size_t)(row0 + r) * D4;
        float a = 0.f;
#pragma unroll
        for (int p = 0; p < 8; ++p) {
            const int j4 = p * 256 + t;
            float4 m = MK4[base + j4];
            if (j4 == mi4) {            // zero reset column before read & write
                if (mic == 0) m.x = 0.f;
                else if (mic == 1) m.y = 0.f;
                else if (mic == 2) m.z = 0.f;
                else m.w = 0.f;
            }
            a += wr[p].x * m.x + wr[p].y * m.y + wr[p].z * m.z + wr[p].w * m.w;
            float4 o;
            o.x = m.x + ak[p].x; o.y = m.y + ak[p].y;
            o.z = m.z + ak[p].z; o.w = m.w + ak[p].w;
            OMK4[base + j4] = o;
        }
        racc[r] = a;
    }

    __shared__ float red[4][R];
    const int lane = t & 63, wid = t >> 6;
#pragma unroll
    for (int r = 0; r < R; ++r) {
        const float v = wred_sum(racc[r]);
        if (lane == 0) red[wid][r] = v;
    }
    __syncthreads();
    if (t < R) out_u[row0 + t] = red[0][t] + red[1][t] + red[2][t] + red[3][t];
}

// ---------- pass C: mu_new = (MU with col mi zeroed) + add_u ----------
__global__ __launch_bounds__(256) void pass_c(const float* __restrict__ MU,
                                              const float* __restrict__ add_u,
                                              const int* __restrict__ mip,
                                              float* __restrict__ out_mu) {
    const int mi = mip[0];
    const int mi4 = mi >> 2, mic = mi & 3;
    const size_t idx = (size_t)blockIdx.x * 256 + threadIdx.x;   // float4 index
    const int j4 = (int)(idx & (D4 - 1));
    float4 m = ((const float4*)MU)[idx];
    const float4 a = ((const float4*)add_u)[j4];
    if (j4 == mi4) {
        if (mic == 0) m.x = 0.f;
        else if (mic == 1) m.y = 0.f;
        else if (mic == 2) m.z = 0.f;
        else m.w = 0.f;
    }
    m.x += a.x; m.y += a.y; m.z += a.z; m.w += a.w;
    ((float4*)out_mu)[idx] = m;
}

extern "C" void kernel_launch(void* const* d_in, const int* in_sizes, int n_in,
                              void* d_out, int out_size, void* d_ws, size_t ws_size,
                              hipStream_t stream) {
    const float* k      = (const float*)d_in[0];
    const float* u      = (const float*)d_in[1];
    const float* MK     = (const float*)d_in[2];
    const float* MU     = (const float*)d_in[3];
    const float* w_w    = (const float*)d_in[4];
    const float* w_u    = (const float*)d_in[5];
    const float* w_lu   = (const float*)d_in[6];
    const float* beta_p = (const float*)d_in[7];

    float* out = (float*)d_out;
    float* o_u   = out;                                    // (1, D)
    float* o_mk  = out + D;                                // (D, D)
    float* o_mu  = out + D + (size_t)D * D;                // (D, D)
    float* o_www = out + D + 2 * (size_t)D * D;            // (1, D)
    float* o_wun = o_www + D;                              // (1, D)
    float* o_wlu = o_wun + D;                              // (1, D)

    float* ws   = (float*)d_ws;
    float* dot  = ws;             // -> w_r after kern_small
    float* sq   = ws + D;         // -> add_k after kern_small
    float* au   = ws + 2 * D;     // add_u
    int*   mip  = (int*)(ws + 3 * D);

    // dot/sq accumulators must start at zero (ws is poisoned with 0xAA)
    hipMemsetAsync(dot, 0, 2 * D * sizeof(float), stream);

    pass_a<<<dim3(8, 128), 256, 0, stream>>>(MK, k, dot, sq);
    kern_small<<<1, 1024, 0, stream>>>(k, u, w_w, w_u, w_lu, beta_p,
                                       dot, sq, au, mip, o_www, o_wun, o_wlu);
    pass_b<<<1024, 256, 0, stream>>>(MK, dot, sq, mip, o_u, o_mk);
    pass_c<<<(D * (size_t)D / 4) / 256, 256, 0, stream>>>(MU, au, mip, o_mu);
}